// Round 8
// baseline (215.936 us; speedup 1.0000x reference)
//
#include <hip/hip_runtime.h>
#include <hip/hip_fp16.h>

#define NROUTES 1152
#define NCAPS   10
#define INCH    8
#define OUTCH   16
#define NBATCH  512
#define NITER   3
#define NPROB   (NBATCH * NCAPS)    // 5120

// ================= Kernel 1: staging (u_hat -> workspace, fp16) =============
// grid = 2304 x 64 threads. Block: route r = bid>>1, batches [(bid&1)*256, +256).
// W row (all c) staged to LDS once, broadcast-read; X coalesced; U scatter-write.
// U layout: [problem = b*10+c][r][o] fp16.
__global__ __launch_bounds__(64, 3)
void k1_stage(const float* __restrict__ X,   // (R, B, I)
              const float* __restrict__ W,   // (R, C, O, I)
              __half* __restrict__ U)
{
    const int lane = threadIdx.x;
    const int r    = blockIdx.x >> 1;
    const int bb   = (blockIdx.x & 1) * 256;

    __shared__ float ws[NCAPS * OUTCH * INCH];   // 1280 floats = 5 KB

    {   // coop load W row: 320 float4s, 5 rounds, fully coalesced
        const float4* src = reinterpret_cast<const float4*>(W) + (size_t)r * 320;
        float4* dst = reinterpret_cast<float4*>(ws);
        #pragma unroll
        for (int i = 0; i < 5; ++i)
            dst[i * 64 + lane] = src[i * 64 + lane];
    }
    __syncthreads();

    // x for 4 batches: b = bb + bi*64 + lane (lane-consecutive -> coalesced)
    float xv[4][INCH];
    #pragma unroll
    for (int bi = 0; bi < 4; ++bi) {
        const float* xp = X + ((size_t)r * NBATCH + (bb + bi * 64 + lane)) * INCH;
        float4 a0 = *reinterpret_cast<const float4*>(xp);
        float4 a1 = *reinterpret_cast<const float4*>(xp + 4);
        xv[bi][0] = a0.x; xv[bi][1] = a0.y; xv[bi][2] = a0.z; xv[bi][3] = a0.w;
        xv[bi][4] = a1.x; xv[bi][5] = a1.y; xv[bi][6] = a1.z; xv[bi][7] = a1.w;
    }

    for (int c = 0; c < NCAPS; ++c) {
        float acc[OUTCH][4];
        #pragma unroll
        for (int o = 0; o < OUTCH; ++o) {
            const float* wp = ws + (c * OUTCH + o) * INCH;
            float4 w0 = *reinterpret_cast<const float4*>(wp);      // LDS broadcast
            float4 w1 = *reinterpret_cast<const float4*>(wp + 4);
            #pragma unroll
            for (int bi = 0; bi < 4; ++bi) {
                float a = w0.x * xv[bi][0];
                a = fmaf(w0.y, xv[bi][1], a);
                a = fmaf(w0.z, xv[bi][2], a);
                a = fmaf(w0.w, xv[bi][3], a);
                a = fmaf(w1.x, xv[bi][4], a);
                a = fmaf(w1.y, xv[bi][5], a);
                a = fmaf(w1.z, xv[bi][6], a);
                a = fmaf(w1.w, xv[bi][7], a);
                acc[o][bi] = a;
            }
        }
        #pragma unroll
        for (int bi = 0; bi < 4; ++bi) {
            const int b = bb + bi * 64 + lane;
            const size_t prob = (size_t)b * NCAPS + c;
            uint4* up = reinterpret_cast<uint4*>(U + (prob * NROUTES + r) * OUTCH);
            uint4 pk0, pk1;
            __half2* p0 = reinterpret_cast<__half2*>(&pk0);
            __half2* p1 = reinterpret_cast<__half2*>(&pk1);
            #pragma unroll
            for (int j = 0; j < 4; ++j) {
                p0[j] = __float22half2_rn(make_float2(acc[2 * j][bi],     acc[2 * j + 1][bi]));
                p1[j] = __float22half2_rn(make_float2(acc[8 + 2 * j][bi], acc[9 + 2 * j][bi]));
            }
            up[0] = pk0;
            up[1] = pk1;
        }
    }
}

// ================= Kernel 2: routing (u in registers, per-problem block) =====
#define K2_TPB 128
#define K2_RPT (NROUTES / K2_TPB)   // 9 routes per thread
__global__ __launch_bounds__(K2_TPB, 3)
void k2_route(const __half* __restrict__ U, float* __restrict__ OUT)
{
    const int t    = threadIdx.x;
    const int wid  = t >> 6;
    const int lane = t & 63;
    const int p    = blockIdx.x;          // problem = b*10 + c

    __shared__ float red[2][17];
    __shared__ float fin[17];

    // load u: routes r = k*128 + t, 32 B each, fully coalesced
    uint4 upk[K2_RPT][2];   // 72 VGPRs of packed fp16
    {
        const uint4* ub = reinterpret_cast<const uint4*>(U + (size_t)p * NROUTES * OUTCH);
        #pragma unroll
        for (int k = 0; k < K2_RPT; ++k) {
            upk[k][0] = ub[(k * K2_TPB + t) * 2 + 0];
            upk[k][1] = ub[(k * K2_TPB + t) * 2 + 1];
        }
    }

    float bij[K2_RPT];
    #pragma unroll
    for (int k = 0; k < K2_RPT; ++k) bij[k] = 0.0f;
    float v[OUTCH];

    #pragma unroll
    for (int it = 0; it < NITER; ++it) {
        float S[OUTCH];
        float Z = 0.0f;
        #pragma unroll
        for (int o = 0; o < OUTCH; ++o) S[o] = 0.0f;

        // fused pass: (b-update + exp) + S accumulate, straight from registers
        #pragma unroll
        for (int k = 0; k < K2_RPT; ++k) {
            float u[OUTCH];
            {
                const __half2* q0 = reinterpret_cast<const __half2*>(&upk[k][0]);
                const __half2* q1 = reinterpret_cast<const __half2*>(&upk[k][1]);
                #pragma unroll
                for (int j = 0; j < 4; ++j) {
                    float2 f = __half22float2(q0[j]);
                    u[2 * j] = f.x; u[2 * j + 1] = f.y;
                    float2 g = __half22float2(q1[j]);
                    u[8 + 2 * j] = g.x; u[9 + 2 * j] = g.y;
                }
            }
            if (it == 0) {
                #pragma unroll
                for (int o = 0; o < OUTCH; ++o) S[o] += u[o];
            } else {
                float d = 0.0f;
                #pragma unroll
                for (int o = 0; o < OUTCH; ++o) d = fmaf(u[o], v[o], d);
                bij[k] += d;
                float e = __expf(bij[k]);
                Z += e;
                #pragma unroll
                for (int o = 0; o < OUTCH; ++o) S[o] = fmaf(e, u[o], S[o]);
            }
        }

        // scatter-halving wave reduce: 17 shuffles for S[16]
        float s;
        {
            float a8[8];
            {
                const int bit = lane & 1;
                #pragma unroll
                for (int i = 0; i < 8; ++i)
                    a8[i] = (bit ? S[i + 8] : S[i]) +
                            __shfl_xor(bit ? S[i] : S[i + 8], 1);
            }
            float a4[4];
            {
                const int bit = lane & 2;
                #pragma unroll
                for (int i = 0; i < 4; ++i)
                    a4[i] = (bit ? a8[i + 4] : a8[i]) +
                            __shfl_xor(bit ? a8[i] : a8[i + 4], 2);
            }
            float a2[2];
            {
                const int bit = lane & 4;
                #pragma unroll
                for (int i = 0; i < 2; ++i)
                    a2[i] = (bit ? a4[i + 2] : a4[i]) +
                            __shfl_xor(bit ? a4[i] : a4[i + 2], 4);
            }
            {
                const int bit = lane & 8;
                s = (bit ? a2[1] : a2[0]) + __shfl_xor(bit ? a2[0] : a2[1], 8);
            }
            s += __shfl_xor(s, 16);
            s += __shfl_xor(s, 32);
        }
        if (it > 0) {
            #pragma unroll
            for (int sh = 1; sh <= 32; sh <<= 1) Z += __shfl_xor(Z, sh);
        }

        if (lane < 16) {
            const int o = ((lane & 1) << 3) | ((lane & 2) << 1) |
                          ((lane & 4) >> 1) | ((lane & 8) >> 3);
            red[wid][o] = s;
        } else if (lane == 16) {
            red[wid][16] = Z;
        }
        __syncthreads();   // B1

        if (t < 17) fin[t] = red[0][t] + red[1][t];
        __syncthreads();   // B2

        // squash (redundant per thread; broadcast from LDS)
        {
            float rZ = (it == 0) ? (1.0f / 1152.0f) : (1.0f / fin[16]);
            float n2 = 0.0f;
            #pragma unroll
            for (int o = 0; o < OUTCH; ++o) {
                float sv = fin[o] * rZ;
                v[o] = sv;
                n2 = fmaf(sv, sv, n2);
            }
            float sc = sqrtf(n2) / (1.0f + n2);
            #pragma unroll
            for (int o = 0; o < OUTCH; ++o) v[o] *= sc;
        }
        // red/fin reuse next iter ordered by next iter's B1/B2.
    }

    if (t == 0) {
        float* op = OUT + (size_t)p * OUTCH;
        #pragma unroll
        for (int o = 0; o < OUTCH; o += 4)
            *reinterpret_cast<float4*>(op + o) =
                make_float4(v[o], v[o + 1], v[o + 2], v[o + 3]);
    }
}

// ================= Fallback: round-7 single kernel (ws too small) ============
#define TPB     576
#define RPT     2
#define NB      4
#define NWAVES  (TPB / 64)

__global__ __launch_bounds__(TPB, 2)
void caps_route_fallback(const float* __restrict__ X,
                         const float* __restrict__ W,
                         float* __restrict__ OUT)
{
    const int t    = threadIdx.x;
    const int wid  = t >> 6;
    const int lane = t & 63;
    const int c    = blockIdx.x / (NBATCH / NB);
    const int b0   = (blockIdx.x % (NBATCH / NB)) * NB;

    __shared__ uint4 uh[NB][RPT * 2][TPB];
    __shared__ float red2[NWAVES][2][17];
    __shared__ float fin2[2][17];

    #pragma unroll
    for (int j = 0; j < RPT; ++j) {
        const int r = t * RPT + j;
        const float* xp = X + ((size_t)r * NBATCH + b0) * INCH;
        float xv[NB][INCH];
        #pragma unroll
        for (int nb = 0; nb < NB; ++nb) {
            float4 a0 = *reinterpret_cast<const float4*>(xp + nb * INCH);
            float4 a1 = *reinterpret_cast<const float4*>(xp + nb * INCH + 4);
            xv[nb][0] = a0.x; xv[nb][1] = a0.y; xv[nb][2] = a0.z; xv[nb][3] = a0.w;
            xv[nb][4] = a1.x; xv[nb][5] = a1.y; xv[nb][6] = a1.z; xv[nb][7] = a1.w;
        }
        const float* wp = W + ((size_t)r * NCAPS + c) * (OUTCH * INCH);
        #pragma unroll
        for (int h = 0; h < 2; ++h) {
            float a[NB][8];
            #pragma unroll
            for (int oi = 0; oi < 8; ++oi) {
                const int o = h * 8 + oi;
                float4 w0 = *reinterpret_cast<const float4*>(wp + o * INCH);
                float4 w1 = *reinterpret_cast<const float4*>(wp + o * INCH + 4);
                #pragma unroll
                for (int nb = 0; nb < NB; ++nb) {
                    float acc = w0.x * xv[nb][0];
                    acc = fmaf(w0.y, xv[nb][1], acc);
                    acc = fmaf(w0.z, xv[nb][2], acc);
                    acc = fmaf(w0.w, xv[nb][3], acc);
                    acc = fmaf(w1.x, xv[nb][4], acc);
                    acc = fmaf(w1.y, xv[nb][5], acc);
                    acc = fmaf(w1.z, xv[nb][6], acc);
                    acc = fmaf(w1.w, xv[nb][7], acc);
                    a[nb][oi] = acc;
                }
            }
            #pragma unroll
            for (int nb = 0; nb < NB; ++nb) {
                uint4 pk;
                __half2* ph = reinterpret_cast<__half2*>(&pk);
                #pragma unroll
                for (int k = 0; k < 4; ++k)
                    ph[k] = __float22half2_rn(make_float2(a[nb][2 * k], a[nb][2 * k + 1]));
                uh[nb][j * 2 + h][t] = pk;
            }
        }
    }

    #pragma unroll
    for (int p = 0; p < NB / 2; ++p) {
        const int nA = 2 * p, nB_ = 2 * p + 1;
        float v0[OUTCH], v1[OUTCH];
        float bA[RPT], bB[RPT];
        #pragma unroll
        for (int j = 0; j < RPT; ++j) { bA[j] = 0.0f; bB[j] = 0.0f; }

        #pragma unroll
        for (int it = 0; it < NITER; ++it) {
            float S0[OUTCH], S1[OUTCH];
            float Z0 = 0.0f, Z1 = 0.0f;
            #pragma unroll
            for (int o = 0; o < OUTCH; ++o) { S0[o] = 0.0f; S1[o] = 0.0f; }

            #pragma unroll
            for (int j = 0; j < RPT; ++j) {
                float uA[OUTCH], uB[OUTCH];
                {
                    uint4 pk0 = uh[nA][j * 2][t];
                    uint4 pk1 = uh[nA][j * 2 + 1][t];
                    const __half2* p0 = reinterpret_cast<const __half2*>(&pk0);
                    const __half2* p1 = reinterpret_cast<const __half2*>(&pk1);
                    #pragma unroll
                    for (int k = 0; k < 4; ++k) {
                        float2 f = __half22float2(p0[k]);
                        uA[2 * k] = f.x; uA[2 * k + 1] = f.y;
                        float2 g = __half22float2(p1[k]);
                        uA[8 + 2 * k] = g.x; uA[8 + 2 * k + 1] = g.y;
                    }
                    uint4 qk0 = uh[nB_][j * 2][t];
                    uint4 qk1 = uh[nB_][j * 2 + 1][t];
                    const __half2* q0 = reinterpret_cast<const __half2*>(&qk0);
                    const __half2* q1 = reinterpret_cast<const __half2*>(&qk1);
                    #pragma unroll
                    for (int k = 0; k < 4; ++k) {
                        float2 f = __half22float2(q0[k]);
                        uB[2 * k] = f.x; uB[2 * k + 1] = f.y;
                        float2 g = __half22float2(q1[k]);
                        uB[8 + 2 * k] = g.x; uB[8 + 2 * k + 1] = g.y;
                    }
                }
                if (it == 0) {
                    #pragma unroll
                    for (int o = 0; o < OUTCH; ++o) { S0[o] += uA[o]; S1[o] += uB[o]; }
                } else {
                    float dA = 0.0f, dB = 0.0f;
                    #pragma unroll
                    for (int o = 0; o < OUTCH; ++o) {
                        dA = fmaf(uA[o], v0[o], dA);
                        dB = fmaf(uB[o], v1[o], dB);
                    }
                    bA[j] += dA; bB[j] += dB;
                    float eA = __expf(bA[j]);
                    float eB = __expf(bB[j]);
                    Z0 += eA; Z1 += eB;
                    #pragma unroll
                    for (int o = 0; o < OUTCH; ++o) {
                        S0[o] = fmaf(eA, uA[o], S0[o]);
                        S1[o] = fmaf(eB, uB[o], S1[o]);
                    }
                }
            }

            float sA, sB;
            {
                float a8[8], b8[8];
                {
                    const int bit = lane & 1;
                    #pragma unroll
                    for (int i = 0; i < 8; ++i) {
                        a8[i] = (bit ? S0[i + 8] : S0[i]) +
                                __shfl_xor(bit ? S0[i] : S0[i + 8], 1);
                        b8[i] = (bit ? S1[i + 8] : S1[i]) +
                                __shfl_xor(bit ? S1[i] : S1[i + 8], 1);
                    }
                }
                float a4[4], b4[4];
                {
                    const int bit = lane & 2;
                    #pragma unroll
                    for (int i = 0; i < 4; ++i) {
                        a4[i] = (bit ? a8[i + 4] : a8[i]) +
                                __shfl_xor(bit ? a8[i] : a8[i + 4], 2);
                        b4[i] = (bit ? b8[i + 4] : b8[i]) +
                                __shfl_xor(bit ? b8[i] : b8[i + 4], 2);
                    }
                }
                float a2[2], b2[2];
                {
                    const int bit = lane & 4;
                    #pragma unroll
                    for (int i = 0; i < 2; ++i) {
                        a2[i] = (bit ? a4[i + 2] : a4[i]) +
                                __shfl_xor(bit ? a4[i] : a4[i + 2], 4);
                        b2[i] = (bit ? b4[i + 2] : b4[i]) +
                                __shfl_xor(bit ? b4[i] : b4[i + 2], 4);
                    }
                }
                {
                    const int bit = lane & 8;
                    sA = (bit ? a2[1] : a2[0]) + __shfl_xor(bit ? a2[0] : a2[1], 8);
                    sB = (bit ? b2[1] : b2[0]) + __shfl_xor(bit ? b2[0] : b2[1], 8);
                }
                sA += __shfl_xor(sA, 16);  sA += __shfl_xor(sA, 32);
                sB += __shfl_xor(sB, 16);  sB += __shfl_xor(sB, 32);
            }
            if (it > 0) {
                #pragma unroll
                for (int sh = 1; sh <= 32; sh <<= 1) {
                    Z0 += __shfl_xor(Z0, sh);
                    Z1 += __shfl_xor(Z1, sh);
                }
            }

            if (lane < 16) {
                const int o = ((lane & 1) << 3) | ((lane & 2) << 1) |
                              ((lane & 4) >> 1) | ((lane & 8) >> 3);
                red2[wid][0][o] = sA;
                red2[wid][1][o] = sB;
            } else if (lane == 16) {
                red2[wid][0][16] = Z0;
                red2[wid][1][16] = Z1;
            }
            __syncthreads();

            if (t < 34) {
                const int nb = t / 17, k = t % 17;
                float s = red2[0][nb][k];
                #pragma unroll
                for (int w = 1; w < NWAVES; ++w) s += red2[w][nb][k];
                fin2[nb][k] = s;
            }
            __syncthreads();

            {
                float rZA = (it == 0) ? (1.0f / 1152.0f) : (1.0f / fin2[0][16]);
                float rZB = (it == 0) ? (1.0f / 1152.0f) : (1.0f / fin2[1][16]);
                float n2A = 0.0f, n2B = 0.0f;
                #pragma unroll
                for (int o = 0; o < OUTCH; ++o) {
                    float sAo = fin2[0][o] * rZA;
                    float sBo = fin2[1][o] * rZB;
                    v0[o] = sAo; n2A = fmaf(sAo, sAo, n2A);
                    v1[o] = sBo; n2B = fmaf(sBo, sBo, n2B);
                }
                float scA = sqrtf(n2A) / (1.0f + n2A);
                float scB = sqrtf(n2B) / (1.0f + n2B);
                #pragma unroll
                for (int o = 0; o < OUTCH; ++o) { v0[o] *= scA; v1[o] *= scB; }
            }
        }

        if (t == 0) {
            float* opA = OUT + ((size_t)(b0 + nA) * NCAPS + c) * OUTCH;
            float* opB = OUT + ((size_t)(b0 + nB_) * NCAPS + c) * OUTCH;
            #pragma unroll
            for (int o = 0; o < OUTCH; o += 4) {
                *reinterpret_cast<float4*>(opA + o) =
                    make_float4(v0[o], v0[o + 1], v0[o + 2], v0[o + 3]);
                *reinterpret_cast<float4*>(opB + o) =
                    make_float4(v1[o], v1[o + 1], v1[o + 2], v1[o + 3]);
            }
        }
        __syncthreads();
    }
}

extern "C" void kernel_launch(void* const* d_in, const int* in_sizes, int n_in,
                              void* d_out, int out_size, void* d_ws, size_t ws_size,
                              hipStream_t stream) {
    const float* X = (const float*)d_in[0];            // (1152, 512, 8)
    const float* W = (const float*)d_in[1];            // (1152, 10, 16, 8)
    float* OUT     = (float*)d_out;                    // (512, 10, 16)

    const size_t need = (size_t)NPROB * NROUTES * OUTCH * sizeof(__half);  // 188.7 MB
    if (ws_size >= need && d_ws != nullptr) {
        __half* U = (__half*)d_ws;
        k1_stage<<<dim3(NROUTES * 2), dim3(64), 0, stream>>>(X, W, U);
        k2_route<<<dim3(NPROB), dim3(K2_TPB), 0, stream>>>(U, OUT);
    } else {
        caps_route_fallback<<<dim3(NCAPS * (NBATCH / NB)), dim3(TPB), 0, stream>>>(X, W, OUT);
    }
}

// Round 9
// 115.071 us; speedup vs baseline: 1.8765x; 1.8765x over previous
//
#include <hip/hip_runtime.h>
#include <hip/hip_fp16.h>

#define NROUTES 1152
#define NCAPS   10
#define INCH    8
#define OUTCH   16
#define NBATCH  512
#define NITER   3
#define NPROB   (NBATCH * NCAPS)    // 5120

// U layout: [prob = b*10+c][half h=0/1][route][8 o] fp16.
//  - k1 store instr: lanes run along route -> 256B dense segments -> FULL 64B
//    lines per instruction -> no L2 write-allocate RMW (round-8 killer).
//  - k2 reads two coalesced streams at uint4 index r and 1152+r.

typedef _Float16 h2 __attribute__((ext_vector_type(2)));

#if defined(__has_builtin)
#if __has_builtin(__builtin_amdgcn_fdot2)
#define HAVE_FDOT2 1
#endif
#endif

__device__ __forceinline__ float dot2acc(h2 a, h2 b, float c) {
#ifdef HAVE_FDOT2
    return __builtin_amdgcn_fdot2(a, b, c, false);
#else
    return c + (float)a[0] * (float)b[0] + (float)a[1] * (float)b[1];
#endif
}

__device__ __forceinline__ h2 to_h2(float a, float b) {
    __half2 t = __float22half2_rn(make_float2(a, b));
    return *reinterpret_cast<h2*>(&t);
}

// ================= Kernel 1: staging (u_hat -> workspace, fp16) =============
#define K1_RCH   16                  // routes per block
#define K1_BCH   16                  // batches per block
#define K1_TPB   256                 // 16 rl x 16 bl
#define K1_ROWB  2576                // LDS bytes per route row (2560 fp16 + 16 pad)
#define K1_UNITS (K1_RCH * 320)      // 16B f32 units in W tile: 5120

__global__ __launch_bounds__(K1_TPB, 3)
void k1_stage(const float* __restrict__ X,   // (R, B, I)
              const float* __restrict__ W,   // (R, C, O, I)
              __half* __restrict__ U)
{
    const int t  = threadIdx.x;
    const int rl = t & 15;
    const int bl = t >> 4;
    // r-fastest: 72 r-chunks, 72%8==0 -> same-r blocks share an XCD L2 for W
    const int r0 = (blockIdx.x % (NROUTES / K1_RCH)) * K1_RCH;
    const int b0 = (blockIdx.x / (NROUTES / K1_RCH)) * K1_BCH;

    __shared__ __align__(16) unsigned char wlds[K1_RCH * K1_ROWB];  // 41216 B

    // ---- stage W tile (16 routes x 5120B f32) -> LDS fp16 (coalesced) ----
    {
        const float4* src = reinterpret_cast<const float4*>(
            W + (size_t)r0 * NCAPS * OUTCH * INCH);
        #pragma unroll
        for (int k = 0; k < K1_UNITS / K1_TPB; ++k) {   // 20 iters
            const int u      = t + k * K1_TPB;
            const int rseg   = u / 320;
            const int within = u % 320;
            float4 w4 = src[u];
            __half2 lo = __float22half2_rn(make_float2(w4.x, w4.y));
            __half2 hi = __float22half2_rn(make_float2(w4.z, w4.w));
            uint2 pk;
            pk.x = *reinterpret_cast<unsigned int*>(&lo);
            pk.y = *reinterpret_cast<unsigned int*>(&hi);
            *reinterpret_cast<uint2*>(wlds + rseg * K1_ROWB + within * 8) = pk;
        }
    }
    __syncthreads();   // the only barrier in k1

    // ---- x for (r0+rl, b0+bl): 8 f32 -> 4x h2 ----
    h2 xh[4];
    {
        const float* xp = X + ((size_t)(r0 + rl) * NBATCH + (b0 + bl)) * INCH;
        float4 xa = *reinterpret_cast<const float4*>(xp);
        float4 xb = *reinterpret_cast<const float4*>(xp + 4);
        xh[0] = to_h2(xa.x, xa.y);
        xh[1] = to_h2(xa.z, xa.w);
        xh[2] = to_h2(xb.x, xb.y);
        xh[3] = to_h2(xb.z, xb.w);
    }

    const unsigned char* wrow = wlds + rl * K1_ROWB;

    for (int c = 0; c < NCAPS; ++c) {
        float acc[OUTCH];
        #pragma unroll
        for (int o = 0; o < OUTCH; ++o) {
            uint4 wv = *reinterpret_cast<const uint4*>(wrow + c * 256 + o * 16);
            const h2* wp = reinterpret_cast<const h2*>(&wv);
            float a = dot2acc(wp[0], xh[0], 0.0f);
            a = dot2acc(wp[1], xh[1], a);
            a = dot2acc(wp[2], xh[2], a);
            a = dot2acc(wp[3], xh[3], a);
            acc[o] = a;
        }
        // pack: pk0 = o0..o7, pk1 = o8..o15 (lo half = even o)
        uint4 pk0, pk1;
        {
            unsigned int* q0 = reinterpret_cast<unsigned int*>(&pk0);
            unsigned int* q1 = reinterpret_cast<unsigned int*>(&pk1);
            #pragma unroll
            for (int j = 0; j < 4; ++j) {
                __half2 a0 = __float22half2_rn(make_float2(acc[2 * j],     acc[2 * j + 1]));
                __half2 a1 = __float22half2_rn(make_float2(acc[8 + 2 * j], acc[9 + 2 * j]));
                q0[j] = *reinterpret_cast<unsigned int*>(&a0);
                q1[j] = *reinterpret_cast<unsigned int*>(&a1);
            }
        }
        // dense stores: lanes rl-consecutive -> 256B segments, full lines
        const size_t prob = (size_t)(b0 + bl) * NCAPS + c;
        uint4* ub = reinterpret_cast<uint4*>(U + prob * (2 * NROUTES * 8));
        ub[r0 + rl]           = pk0;   // half 0
        ub[NROUTES + r0 + rl] = pk1;   // half 1
    }
}

// ================= Kernel 2: routing (u in registers, per-problem block) =====
#define K2_TPB 128
#define K2_RPT (NROUTES / K2_TPB)   // 9 routes per thread
__global__ __launch_bounds__(K2_TPB, 3)
void k2_route(const __half* __restrict__ U, float* __restrict__ OUT)
{
    const int t    = threadIdx.x;
    const int wid  = t >> 6;
    const int lane = t & 63;
    const int p    = blockIdx.x;          // problem = b*10 + c

    __shared__ float red[2][17];
    __shared__ float fin[17];

    // load u: routes r = k*128 + t; two coalesced half-streams
    uint4 upk[K2_RPT][2];
    {
        const uint4* ub = reinterpret_cast<const uint4*>(U + (size_t)p * (2 * NROUTES * 8));
        #pragma unroll
        for (int k = 0; k < K2_RPT; ++k) {
            upk[k][0] = ub[k * K2_TPB + t];
            upk[k][1] = ub[NROUTES + k * K2_TPB + t];
        }
    }

    float bij[K2_RPT];
    #pragma unroll
    for (int k = 0; k < K2_RPT; ++k) bij[k] = 0.0f;
    float v[OUTCH];

    #pragma unroll
    for (int it = 0; it < NITER; ++it) {
        float S[OUTCH];
        float Z = 0.0f;
        #pragma unroll
        for (int o = 0; o < OUTCH; ++o) S[o] = 0.0f;

        // fused pass: (b-update + exp) + S accumulate, straight from registers
        #pragma unroll
        for (int k = 0; k < K2_RPT; ++k) {
            float u[OUTCH];
            {
                const __half2* q0 = reinterpret_cast<const __half2*>(&upk[k][0]);
                const __half2* q1 = reinterpret_cast<const __half2*>(&upk[k][1]);
                #pragma unroll
                for (int j = 0; j < 4; ++j) {
                    float2 f = __half22float2(q0[j]);
                    u[2 * j] = f.x; u[2 * j + 1] = f.y;
                    float2 g = __half22float2(q1[j]);
                    u[8 + 2 * j] = g.x; u[9 + 2 * j] = g.y;
                }
            }
            if (it == 0) {
                #pragma unroll
                for (int o = 0; o < OUTCH; ++o) S[o] += u[o];
            } else {
                float d = 0.0f;
                #pragma unroll
                for (int o = 0; o < OUTCH; ++o) d = fmaf(u[o], v[o], d);
                bij[k] += d;
                float e = __expf(bij[k]);
                Z += e;
                #pragma unroll
                for (int o = 0; o < OUTCH; ++o) S[o] = fmaf(e, u[o], S[o]);
            }
        }

        // scatter-halving wave reduce: 17 shuffles for S[16]
        float s;
        {
            float a8[8];
            {
                const int bit = lane & 1;
                #pragma unroll
                for (int i = 0; i < 8; ++i)
                    a8[i] = (bit ? S[i + 8] : S[i]) +
                            __shfl_xor(bit ? S[i] : S[i + 8], 1);
            }
            float a4[4];
            {
                const int bit = lane & 2;
                #pragma unroll
                for (int i = 0; i < 4; ++i)
                    a4[i] = (bit ? a8[i + 4] : a8[i]) +
                            __shfl_xor(bit ? a8[i] : a8[i + 4], 2);
            }
            float a2[2];
            {
                const int bit = lane & 4;
                #pragma unroll
                for (int i = 0; i < 2; ++i)
                    a2[i] = (bit ? a4[i + 2] : a4[i]) +
                            __shfl_xor(bit ? a4[i] : a4[i + 2], 4);
            }
            {
                const int bit = lane & 8;
                s = (bit ? a2[1] : a2[0]) + __shfl_xor(bit ? a2[0] : a2[1], 8);
            }
            s += __shfl_xor(s, 16);
            s += __shfl_xor(s, 32);
        }
        if (it > 0) {
            #pragma unroll
            for (int sh = 1; sh <= 32; sh <<= 1) Z += __shfl_xor(Z, sh);
        }

        if (lane < 16) {
            const int o = ((lane & 1) << 3) | ((lane & 2) << 1) |
                          ((lane & 4) >> 1) | ((lane & 8) >> 3);
            red[wid][o] = s;
        } else if (lane == 16) {
            red[wid][16] = Z;
        }
        __syncthreads();   // B1

        if (t < 17) fin[t] = red[0][t] + red[1][t];
        __syncthreads();   // B2

        // squash (redundant per thread; broadcast from LDS)
        {
            float rZ = (it == 0) ? (1.0f / 1152.0f) : (1.0f / fin[16]);
            float n2 = 0.0f;
            #pragma unroll
            for (int o = 0; o < OUTCH; ++o) {
                float sv = fin[o] * rZ;
                v[o] = sv;
                n2 = fmaf(sv, sv, n2);
            }
            float sc = sqrtf(n2) / (1.0f + n2);
            #pragma unroll
            for (int o = 0; o < OUTCH; ++o) v[o] *= sc;
        }
        // red/fin reuse next iter ordered by next iter's B1/B2.
    }

    if (t == 0) {
        float* op = OUT + (size_t)p * OUTCH;
        #pragma unroll
        for (int o = 0; o < OUTCH; o += 4)
            *reinterpret_cast<float4*>(op + o) =
                make_float4(v[o], v[o + 1], v[o + 2], v[o + 3]);
    }
}

extern "C" void kernel_launch(void* const* d_in, const int* in_sizes, int n_in,
                              void* d_out, int out_size, void* d_ws, size_t ws_size,
                              hipStream_t stream) {
    const float* X = (const float*)d_in[0];            // (1152, 512, 8)
    const float* W = (const float*)d_in[1];            // (1152, 10, 16, 8)
    float* OUT     = (float*)d_out;                    // (512, 10, 16)
    __half* U      = (__half*)d_ws;                    // 188.7 MB (proven sufficient in round 8)

    k1_stage<<<dim3((NROUTES / K1_RCH) * (NBATCH / K1_BCH)), dim3(K1_TPB), 0, stream>>>(X, W, U);
    k2_route<<<dim3(NPROB), dim3(K2_TPB), 0, stream>>>(U, OUT);
}

// Round 10
// 92.611 us; speedup vs baseline: 2.3317x; 1.2425x over previous
//
#include <hip/hip_runtime.h>
#include <hip/hip_fp16.h>

#define NROUTES 1152
#define NCAPS   10
#define INCH    8
#define OUTCH   16
#define NBATCH  512
#define NITER   3
#define NPROB   (NBATCH * NCAPS)    // 5120

// U layout: [prob = b*10+c][half h=0/1][route][8 o] fp16.
//  - k1 store instr: lanes run along route -> 256B dense segments -> FULL 64B
//    lines per instruction -> no L2 write-allocate RMW (round-8 lesson).
//  - k2 reads two coalesced streams at uint4 index r and 1152+r.

typedef _Float16 h2 __attribute__((ext_vector_type(2)));

#if defined(__has_builtin)
#if __has_builtin(__builtin_amdgcn_fdot2)
#define HAVE_FDOT2 1
#endif
#endif

__device__ __forceinline__ float dot2acc(h2 a, h2 b, float c) {
#ifdef HAVE_FDOT2
    return __builtin_amdgcn_fdot2(a, b, c, false);
#else
    return c + (float)a[0] * (float)b[0] + (float)a[1] * (float)b[1];
#endif
}

__device__ __forceinline__ h2 to_h2(float a, float b) {
    __half2 t = __float22half2_rn(make_float2(a, b));
    return *reinterpret_cast<h2*>(&t);
}

// ================= Kernel 1: staging (u_hat -> workspace, fp16) =============
// Unchanged from round 9 (measured ~36us, ~5.9 TB/s effective -> near ceiling).
#define K1_RCH   16                  // routes per block
#define K1_BCH   16                  // batches per block
#define K1_TPB   256                 // 16 rl x 16 bl
#define K1_ROWB  2576                // LDS bytes per route row (2560 fp16 + 16 pad)
#define K1_UNITS (K1_RCH * 320)      // 16B f32 units in W tile: 5120

__global__ __launch_bounds__(K1_TPB, 3)
void k1_stage(const float* __restrict__ X,   // (R, B, I)
              const float* __restrict__ W,   // (R, C, O, I)
              __half* __restrict__ U)
{
    const int t  = threadIdx.x;
    const int rl = t & 15;
    const int bl = t >> 4;
    const int r0 = (blockIdx.x % (NROUTES / K1_RCH)) * K1_RCH;
    const int b0 = (blockIdx.x / (NROUTES / K1_RCH)) * K1_BCH;

    __shared__ __align__(16) unsigned char wlds[K1_RCH * K1_ROWB];  // 41216 B

    {   // stage W tile (16 routes x 5120B f32) -> LDS fp16 (coalesced)
        const float4* src = reinterpret_cast<const float4*>(
            W + (size_t)r0 * NCAPS * OUTCH * INCH);
        #pragma unroll
        for (int k = 0; k < K1_UNITS / K1_TPB; ++k) {   // 20 iters
            const int u      = t + k * K1_TPB;
            const int rseg   = u / 320;
            const int within = u % 320;
            float4 w4 = src[u];
            __half2 lo = __float22half2_rn(make_float2(w4.x, w4.y));
            __half2 hi = __float22half2_rn(make_float2(w4.z, w4.w));
            uint2 pk;
            pk.x = *reinterpret_cast<unsigned int*>(&lo);
            pk.y = *reinterpret_cast<unsigned int*>(&hi);
            *reinterpret_cast<uint2*>(wlds + rseg * K1_ROWB + within * 8) = pk;
        }
    }
    __syncthreads();   // the only barrier in k1

    h2 xh[4];
    {
        const float* xp = X + ((size_t)(r0 + rl) * NBATCH + (b0 + bl)) * INCH;
        float4 xa = *reinterpret_cast<const float4*>(xp);
        float4 xb = *reinterpret_cast<const float4*>(xp + 4);
        xh[0] = to_h2(xa.x, xa.y);
        xh[1] = to_h2(xa.z, xa.w);
        xh[2] = to_h2(xb.x, xb.y);
        xh[3] = to_h2(xb.z, xb.w);
    }

    const unsigned char* wrow = wlds + rl * K1_ROWB;

    for (int c = 0; c < NCAPS; ++c) {
        float acc[OUTCH];
        #pragma unroll
        for (int o = 0; o < OUTCH; ++o) {
            uint4 wv = *reinterpret_cast<const uint4*>(wrow + c * 256 + o * 16);
            const h2* wp = reinterpret_cast<const h2*>(&wv);
            float a = dot2acc(wp[0], xh[0], 0.0f);
            a = dot2acc(wp[1], xh[1], a);
            a = dot2acc(wp[2], xh[2], a);
            a = dot2acc(wp[3], xh[3], a);
            acc[o] = a;
        }
        uint4 pk0, pk1;
        {
            unsigned int* q0 = reinterpret_cast<unsigned int*>(&pk0);
            unsigned int* q1 = reinterpret_cast<unsigned int*>(&pk1);
            #pragma unroll
            for (int j = 0; j < 4; ++j) {
                __half2 a0 = __float22half2_rn(make_float2(acc[2 * j],     acc[2 * j + 1]));
                __half2 a1 = __float22half2_rn(make_float2(acc[8 + 2 * j], acc[9 + 2 * j]));
                q0[j] = *reinterpret_cast<unsigned int*>(&a0);
                q1[j] = *reinterpret_cast<unsigned int*>(&a1);
            }
        }
        const size_t prob = (size_t)(b0 + bl) * NCAPS + c;
        uint4* ub = reinterpret_cast<uint4*>(U + prob * (2 * NROUTES * 8));
        ub[r0 + rl]           = pk0;   // half 0
        ub[NROUTES + r0 + rl] = pk1;   // half 1
    }
}

// ================= Kernel 2: routing =========================================
// Round 10: TPB 128->384, RPT 9->3. Round 9's RPT=9 needed ~125 live regs but
// the allocator's favorite bin is 84 -> 100 MB of spill. At RPT=3 the live set
// is ~70 regs (upk 24 + S 16 + v 16 + bij 3 + temps) -> fits the 84 bin clean.
#define K2_TPB  384                 // 6 waves
#define K2_RPT  (NROUTES / K2_TPB)  // 3 routes per thread
#define K2_NW   (K2_TPB / 64)

__global__ __launch_bounds__(K2_TPB, 2)
void k2_route(const __half* __restrict__ U, float* __restrict__ OUT)
{
    const int t    = threadIdx.x;
    const int wid  = t >> 6;
    const int lane = t & 63;
    const int p    = blockIdx.x;          // problem = b*10 + c

    __shared__ float red[K2_NW][17];
    __shared__ float fin[17];

    // load u: routes r = k*384 + t; two coalesced half-streams (24 VGPRs)
    uint4 upk[K2_RPT][2];
    {
        const uint4* ub = reinterpret_cast<const uint4*>(U + (size_t)p * (2 * NROUTES * 8));
        #pragma unroll
        for (int k = 0; k < K2_RPT; ++k) {
            upk[k][0] = ub[k * K2_TPB + t];
            upk[k][1] = ub[NROUTES + k * K2_TPB + t];
        }
    }

    float bij[K2_RPT];
    #pragma unroll
    for (int k = 0; k < K2_RPT; ++k) bij[k] = 0.0f;
    float v[OUTCH];

    #pragma unroll
    for (int it = 0; it < NITER; ++it) {
        float S[OUTCH];
        float Z = 0.0f;
        #pragma unroll
        for (int o = 0; o < OUTCH; ++o) S[o] = 0.0f;

        // fused pass: (b-update + exp) + S accumulate, straight from registers
        #pragma unroll
        for (int k = 0; k < K2_RPT; ++k) {
            float u[OUTCH];
            {
                const __half2* q0 = reinterpret_cast<const __half2*>(&upk[k][0]);
                const __half2* q1 = reinterpret_cast<const __half2*>(&upk[k][1]);
                #pragma unroll
                for (int j = 0; j < 4; ++j) {
                    float2 f = __half22float2(q0[j]);
                    u[2 * j] = f.x; u[2 * j + 1] = f.y;
                    float2 g = __half22float2(q1[j]);
                    u[8 + 2 * j] = g.x; u[9 + 2 * j] = g.y;
                }
            }
            if (it == 0) {
                #pragma unroll
                for (int o = 0; o < OUTCH; ++o) S[o] += u[o];
            } else {
                float d = 0.0f;
                #pragma unroll
                for (int o = 0; o < OUTCH; ++o) d = fmaf(u[o], v[o], d);
                bij[k] += d;
                float e = __expf(bij[k]);
                Z += e;
                #pragma unroll
                for (int o = 0; o < OUTCH; ++o) S[o] = fmaf(e, u[o], S[o]);
            }
        }

        // scatter-halving wave reduce: 17 shuffles for S[16]
        float s;
        {
            float a8[8];
            {
                const int bit = lane & 1;
                #pragma unroll
                for (int i = 0; i < 8; ++i)
                    a8[i] = (bit ? S[i + 8] : S[i]) +
                            __shfl_xor(bit ? S[i] : S[i + 8], 1);
            }
            float a4[4];
            {
                const int bit = lane & 2;
                #pragma unroll
                for (int i = 0; i < 4; ++i)
                    a4[i] = (bit ? a8[i + 4] : a8[i]) +
                            __shfl_xor(bit ? a8[i] : a8[i + 4], 2);
            }
            float a2[2];
            {
                const int bit = lane & 4;
                #pragma unroll
                for (int i = 0; i < 2; ++i)
                    a2[i] = (bit ? a4[i + 2] : a4[i]) +
                            __shfl_xor(bit ? a4[i] : a4[i + 2], 4);
            }
            {
                const int bit = lane & 8;
                s = (bit ? a2[1] : a2[0]) + __shfl_xor(bit ? a2[0] : a2[1], 8);
            }
            s += __shfl_xor(s, 16);
            s += __shfl_xor(s, 32);
        }
        if (it > 0) {
            #pragma unroll
            for (int sh = 1; sh <= 32; sh <<= 1) Z += __shfl_xor(Z, sh);
        }

        if (lane < 16) {
            const int o = ((lane & 1) << 3) | ((lane & 2) << 1) |
                          ((lane & 4) >> 1) | ((lane & 8) >> 3);
            red[wid][o] = s;
        } else if (lane == 16) {
            red[wid][16] = Z;
        }
        __syncthreads();   // B1

        if (t < 17) {
            float ss = red[0][t];
            #pragma unroll
            for (int w = 1; w < K2_NW; ++w) ss += red[w][t];
            fin[t] = ss;
        }
        __syncthreads();   // B2

        // squash (redundant per thread; broadcast from LDS)
        {
            float rZ = (it == 0) ? (1.0f / 1152.0f) : (1.0f / fin[16]);
            float n2 = 0.0f;
            #pragma unroll
            for (int o = 0; o < OUTCH; ++o) {
                float sv = fin[o] * rZ;
                v[o] = sv;
                n2 = fmaf(sv, sv, n2);
            }
            float sc = sqrtf(n2) / (1.0f + n2);
            #pragma unroll
            for (int o = 0; o < OUTCH; ++o) v[o] *= sc;
        }
        // red/fin reuse next iter ordered by next iter's B1/B2.
    }

    if (t == 0) {
        float* op = OUT + (size_t)p * OUTCH;
        #pragma unroll
        for (int o = 0; o < OUTCH; o += 4)
            *reinterpret_cast<float4*>(op + o) =
                make_float4(v[o], v[o + 1], v[o + 2], v[o + 3]);
    }
}

extern "C" void kernel_launch(void* const* d_in, const int* in_sizes, int n_in,
                              void* d_out, int out_size, void* d_ws, size_t ws_size,
                              hipStream_t stream) {
    const float* X = (const float*)d_in[0];            // (1152, 512, 8)
    const float* W = (const float*)d_in[1];            // (1152, 10, 16, 8)
    float* OUT     = (float*)d_out;                    // (512, 10, 16)
    __half* U      = (__half*)d_ws;                    // 188.7 MB (fits ws, round 8/9)

    k1_stage<<<dim3((NROUTES / K1_RCH) * (NBATCH / K1_BCH)), dim3(K1_TPB), 0, stream>>>(X, W, U);
    k2_route<<<dim3(NPROB), dim3(K2_TPB), 0, stream>>>(U, OUT);
}